// Round 6
// baseline (1131.716 us; speedup 1.0000x reference)
//
#include <hip/hip_runtime.h>
#include <hip/hip_bf16.h>
#include <math.h>

#define NNODES 50000
#define NPAD   50176              // 392*128, padded rows for MFMA tile overrun
#define NEDGES 800000
#define NHOPS  4
#define NF     256
#define NH     128
#define NO     64

#define CONVX_BLOCKS 12500        // NNODES*NF/4/256
#define CONVW_BLOCKS 512          // NHOPS*NH*NF/256
#define HIST_BLOCKS  12500        // (NEDGES/256)*NHOPS
#define LIN_PER_HOP  391          // ceil(NNODES/128)
#define LIN_BLOCKS   (LIN_PER_HOP * NHOPS)     // 1564
#define SCAT_BLOCKS  12500        // (NEDGES/256)*NHOPS
#define PC_BLOCKS    (LIN_BLOCKS + SCAT_BLOCKS)  // 14064
#define LIN_SPAN     (LIN_BLOCKS * 8)            // 12512: linears at bx%8==0 below this

typedef __attribute__((ext_vector_type(8))) short bfrag_t;   // 8 x bf16
typedef __attribute__((ext_vector_type(4))) float facc_t;    // 4 x f32

static __device__ __forceinline__ unsigned short f2bf(float f) {
  unsigned int u = __float_as_uint(f);
  unsigned int r = (u + 0x7fffu + ((u >> 16) & 1u)) >> 16;
  return (unsigned short)r;
}
static __device__ __forceinline__ float bf2f_lo(unsigned int u) {
  return __uint_as_float(u << 16);
}
static __device__ __forceinline__ float bf2f_hi(unsigned int u) {
  return __uint_as_float(u & 0xffff0000u);
}

// ---------------------------------------------------------------------------
// Phase A (fused): convx | convw | hist. All independent.
// ---------------------------------------------------------------------------
__global__ __launch_bounds__(256) void phaseA_kernel(
    const float* __restrict__ x, unsigned short* __restrict__ xb,
    const float* __restrict__ W, unsigned short* __restrict__ Wt,
    const int* __restrict__ erows, int* __restrict__ counts) {
  const int bx = blockIdx.x;
  const int t  = threadIdx.x;
  if (bx < CONVX_BLOCKS) {
    const size_t i = ((size_t)bx * 256 + t) * 4;
    float4 v = *(const float4*)&x[i];
    ushort4 o;
    o.x = f2bf(v.x); o.y = f2bf(v.y); o.z = f2bf(v.z); o.w = f2bf(v.w);
    *(ushort4*)&xb[i] = o;
  } else if (bx < CONVX_BLOCKS + CONVW_BLOCKS) {
    const int i = (bx - CONVX_BLOCKS) * 256 + t;
    const int k = i / (NH * NF);
    const int rem = i - k * NH * NF;
    const int n = rem / NF;
    const int f = rem - n * NF;
    Wt[i] = f2bf(W[(size_t)k * NF * NH + (size_t)f * NH + n]);
  } else {
    const int id  = bx - (CONVX_BLOCKS + CONVW_BLOCKS);
    const int hop = id / 3125;
    const int e   = (id - hop * 3125) * 256 + t;
    const int r = erows[(size_t)hop * NEDGES + e];
    atomicAdd(&counts[hop * NNODES + r], 1);
  }
}

// ---------------------------------------------------------------------------
// CSR build step 2: exclusive scan per hop. 8 items/thread -> 7 chunk iters.
// ---------------------------------------------------------------------------
__global__ __launch_bounds__(1024) void scan_kernel(
    const int* __restrict__ counts, int* __restrict__ offs,
    int* __restrict__ cursor) {
  const int hop  = blockIdx.x;
  const int t    = threadIdx.x;
  const int lane = t & 63;
  const int wid  = t >> 6;
  __shared__ int wsum[16];
  __shared__ int carry_s;
  if (t == 0) carry_s = 0;
  __syncthreads();
  const int CH  = 8192;
  const int nch = (NNODES + CH - 1) / CH;     // 7
  for (int ch = 0; ch < nch; ++ch) {
    const int i0 = ch * CH + t * 8;
    int v[8];
    if (i0 + 7 < NNODES) {
      int4 a = *(const int4*)&counts[hop * NNODES + i0];
      int4 b = *(const int4*)&counts[hop * NNODES + i0 + 4];
      v[0]=a.x; v[1]=a.y; v[2]=a.z; v[3]=a.w;
      v[4]=b.x; v[5]=b.y; v[6]=b.z; v[7]=b.w;
    } else {
#pragma unroll
      for (int j = 0; j < 8; ++j)
        v[j] = (i0 + j < NNODES) ? counts[hop * NNODES + i0 + j] : 0;
    }
    int l[8];
    int run = 0;
#pragma unroll
    for (int j = 0; j < 8; ++j) { run += v[j]; l[j] = run; }   // inclusive
    int s = run;
#pragma unroll
    for (int d = 1; d < 64; d <<= 1) {
      int n = __shfl_up(s, d, 64);
      if (lane >= d) s += n;
    }
    if (lane == 63) wsum[wid] = s;
    __syncthreads();
    if (t < 16) {
      int ws = wsum[t];
#pragma unroll
      for (int d = 1; d < 16; d <<= 1) {
        int n = __shfl_up(ws, d, 16);
        if (t >= d) ws += n;
      }
      wsum[t] = ws;
    }
    __syncthreads();
    const int base = carry_s + (wid ? wsum[wid - 1] : 0) + (s - run);
    if (i0 + 7 < NNODES) {
      int4 o0 = make_int4(base, base + l[0], base + l[1], base + l[2]);
      int4 o1 = make_int4(base + l[3], base + l[4], base + l[5], base + l[6]);
      *(int4*)&offs[hop * (NNODES + 1) + i0]     = o0;
      *(int4*)&offs[hop * (NNODES + 1) + i0 + 4] = o1;
      *(int4*)&cursor[hop * NNODES + i0]     = o0;
      *(int4*)&cursor[hop * NNODES + i0 + 4] = o1;
    } else {
#pragma unroll
      for (int j = 0; j < 8; ++j) {
        if (i0 + j < NNODES) {
          const int excl = base + (l[j] - v[j]);
          offs[hop * (NNODES + 1) + i0 + j] = excl;
          cursor[hop * NNODES + i0 + j]     = excl;
        }
      }
    }
    __syncthreads();
    if (t == 0) carry_s += wsum[15];
    __syncthreads();
  }
  if (t == 0) offs[hop * (NNODES + 1) + NNODES] = carry_s;
}

// ---------------------------------------------------------------------------
// Phase C (fused, INTERLEAVED): every 8th block (below LIN_SPAN) is linear,
// rest scatter — each CU hosts a mix so MFMA runs under the scatter latency
// shadow (m114: pipes co-schedule across waves).
// ---------------------------------------------------------------------------
__global__ __launch_bounds__(256) void phaseC_kernel(
    const unsigned short* __restrict__ xb, const unsigned short* __restrict__ Wt,
    const float* __restrict__ b, unsigned short* __restrict__ slots,
    const int* __restrict__ erows, const int* __restrict__ ecols,
    const float* __restrict__ evals, int* __restrict__ cursor,
    unsigned long long* __restrict__ ecsr) {
  const int bx = blockIdx.x;
  const int t  = threadIdx.x;
  const bool is_lin = ((bx & 7) == 0) && (bx < LIN_SPAN);
  if (is_lin) {
    const int lb  = bx >> 3;                 // 0..1563
    const int hop = lb / LIN_PER_HOP;
    const int mb  = lb - hop * LIN_PER_HOP;
    const unsigned short* Wk = Wt + (size_t)hop * NH * NF;
    const float* bk = b + hop * NH;
    unsigned short* hb = slots + (size_t)(hop + 1) * NNODES * NH;

    const int lane = t & 63;
    const int wave = t >> 6;
    const int wm   = (wave >> 1) * 64;
    const int wn   = (wave & 1) * 64;
    const int m0   = mb * 128;
    const int l15  = lane & 15;
    const int quad = lane >> 4;

    facc_t acc[4][4];
#pragma unroll
    for (int i = 0; i < 4; ++i)
#pragma unroll
      for (int j = 0; j < 4; ++j) {
        facc_t z = {0.f, 0.f, 0.f, 0.f};
        acc[i][j] = z;
      }

#pragma unroll
    for (int k0 = 0; k0 < NF; k0 += 32) {
      bfrag_t a[4], bb[4];
#pragma unroll
      for (int mi = 0; mi < 4; ++mi) {
        const int m = m0 + wm + mi * 16 + l15;
        a[mi] = *(const bfrag_t*)&xb[(size_t)m * NF + k0 + quad * 8];
      }
#pragma unroll
      for (int ni = 0; ni < 4; ++ni) {
        const int n = wn + ni * 16 + l15;
        bb[ni] = *(const bfrag_t*)&Wk[(size_t)n * NF + k0 + quad * 8];
      }
#pragma unroll
      for (int mi = 0; mi < 4; ++mi)
#pragma unroll
        for (int ni = 0; ni < 4; ++ni)
          acc[mi][ni] = __builtin_amdgcn_mfma_f32_16x16x32_bf16(
              a[mi], bb[ni], acc[mi][ni], 0, 0, 0);
    }

#pragma unroll
    for (int ni = 0; ni < 4; ++ni) {
      const int n = wn + ni * 16 + l15;
      const float bias = bk[n];
#pragma unroll
      for (int mi = 0; mi < 4; ++mi) {
#pragma unroll
        for (int r = 0; r < 4; ++r) {
          const int m = m0 + wm + mi * 16 + quad * 4 + r;
          if (m < NNODES) hb[(size_t)m * NH + n] = f2bf(acc[mi][ni][r] + bias);
        }
      }
    }
  } else {
    const int nlin = (bx < LIN_SPAN) ? ((bx >> 3) + 1) : LIN_BLOCKS;
    const int id   = bx - nlin;              // 0..12499
    const int hop  = id / 3125;
    const int e    = (id - hop * 3125) * 256 + t;
    const size_t g = (size_t)hop * NEDGES + e;
    const int r = erows[g];
    const int pos = atomicAdd(&cursor[hop * NNODES + r], 1);
    const unsigned long long pk =
        ((unsigned long long)__float_as_uint(evals[g]) << 32) |
        (unsigned int)ecols[g];
    __builtin_nontemporal_store(pk, &ecsr[(size_t)hop * NEDGES + pos]);
  }
}

// ---------------------------------------------------------------------------
// Gather SpMM (ONE HOP per dispatch — sequential dispatches enforce the
// hb[k]/agg[k] slot-aliasing dependency; fusing hops raced in R5).
// 1 wave/row; wave = 4 edge-groups x 16 lanes x 16B; 16 edges in flight.
// ---------------------------------------------------------------------------
__global__ __launch_bounds__(256) void gather_kernel(
    const int* __restrict__ offs, const int2* __restrict__ ecsr,
    const unsigned short* __restrict__ hb, unsigned short* __restrict__ aggb) {
  const int t    = threadIdx.x;
  const int lane = t & 63;
  const int wid  = t >> 6;
  const int r = blockIdx.x * 4 + wid;
  const int g  = lane >> 4;    // edge subgroup 0..3
  const int sl = lane & 15;    // feature slice: feats sl*8 .. sl*8+7
  const int s = offs[r];
  const int e = offs[r + 1];

  float acc[8];
#pragma unroll
  for (int j = 0; j < 8; ++j) acc[j] = 0.f;

  for (int p = s; p < e; p += 16) {
    int2 ed[4];
#pragma unroll
    for (int q = 0; q < 4; ++q) {
      const int idx = p + q * 4 + g;
      ed[q] = (idx < e) ? ecsr[idx] : make_int2(0, 0);
    }
    uint4 hv[4];
#pragma unroll
    for (int q = 0; q < 4; ++q)
      hv[q] = *(const uint4*)&hb[(size_t)ed[q].x * NH + sl * 8];
#pragma unroll
    for (int q = 0; q < 4; ++q) {
      const float v = __int_as_float(ed[q].y);
      acc[0] += v * bf2f_lo(hv[q].x);
      acc[1] += v * bf2f_hi(hv[q].x);
      acc[2] += v * bf2f_lo(hv[q].y);
      acc[3] += v * bf2f_hi(hv[q].y);
      acc[4] += v * bf2f_lo(hv[q].z);
      acc[5] += v * bf2f_hi(hv[q].z);
      acc[6] += v * bf2f_lo(hv[q].w);
      acc[7] += v * bf2f_hi(hv[q].w);
    }
  }

#pragma unroll
  for (int j = 0; j < 8; ++j) {
    acc[j] += __shfl_xor(acc[j], 16, 64);
    acc[j] += __shfl_xor(acc[j], 32, 64);
  }

  if (g == 0) {
    uint4 o;
    o.x = (unsigned)f2bf(acc[0]) | ((unsigned)f2bf(acc[1]) << 16);
    o.y = (unsigned)f2bf(acc[2]) | ((unsigned)f2bf(acc[3]) << 16);
    o.z = (unsigned)f2bf(acc[4]) | ((unsigned)f2bf(acc[5]) << 16);
    o.w = (unsigned)f2bf(acc[6]) | ((unsigned)f2bf(acc[7]) << 16);
    *(uint4*)&aggb[(size_t)r * NH + sl * 8] = o;
  }
}

// ---------------------------------------------------------------------------
// Output: out[n][o] = b_out[o] + sum_f elu(concat[n][f]) * W_out[f][o]
// ---------------------------------------------------------------------------
__global__ __launch_bounds__(64) void out_kernel(
    const unsigned short* __restrict__ aggb, const float* __restrict__ Wout,
    const float* __restrict__ bout, float* __restrict__ out) {
  __shared__ float zs[16 * 516];
  const int t  = threadIdx.x;
  const int n0 = blockIdx.x * 16;

#pragma unroll
  for (int cch = 0; cch < 32; ++cch) {
    const int flat = cch * 256 + t * 4;
    const int n_l  = flat >> 9;
    const int f    = flat & 511;
    const int k    = f >> 7;
    const int j    = f & 127;
    const uint2 u = *(const uint2*)&aggb[((size_t)k * NNODES + n0 + n_l) * NH + j];
    float4 v = make_float4(bf2f_lo(u.x), bf2f_hi(u.x), bf2f_lo(u.y), bf2f_hi(u.y));
    v.x = v.x > 0.f ? v.x : (expf(v.x) - 1.f);
    v.y = v.y > 0.f ? v.y : (expf(v.y) - 1.f);
    v.z = v.z > 0.f ? v.z : (expf(v.z) - 1.f);
    v.w = v.w > 0.f ? v.w : (expf(v.w) - 1.f);
    *(float4*)&zs[n_l * 516 + f] = v;
  }
  __syncthreads();

  const int og = t & 15;
  const int ng = t >> 4;
  float acc[4][4];
#pragma unroll
  for (int i = 0; i < 4; ++i)
#pragma unroll
    for (int o = 0; o < 4; ++o) acc[i][o] = 0.f;

  for (int fq = 0; fq < 128; ++fq) {
    const int f = fq * 4;
    float4 z[4], w[4];
#pragma unroll
    for (int i = 0; i < 4; ++i)
      z[i] = *(float4*)&zs[(ng * 4 + i) * 516 + f];
#pragma unroll
    for (int u = 0; u < 4; ++u)
      w[u] = *(const float4*)&Wout[(size_t)(f + u) * NO + og * 4];
    float zv[4][4] = {{z[0].x, z[0].y, z[0].z, z[0].w},
                      {z[1].x, z[1].y, z[1].z, z[1].w},
                      {z[2].x, z[2].y, z[2].z, z[2].w},
                      {z[3].x, z[3].y, z[3].z, z[3].w}};
    float wv[4][4] = {{w[0].x, w[0].y, w[0].z, w[0].w},
                      {w[1].x, w[1].y, w[1].z, w[1].w},
                      {w[2].x, w[2].y, w[2].z, w[2].w},
                      {w[3].x, w[3].y, w[3].z, w[3].w}};
#pragma unroll
    for (int i = 0; i < 4; ++i)
#pragma unroll
      for (int u = 0; u < 4; ++u)
#pragma unroll
        for (int o = 0; o < 4; ++o) acc[i][o] += zv[i][u] * wv[u][o];
  }

  float bo[4];
#pragma unroll
  for (int o = 0; o < 4; ++o) bo[o] = bout[og * 4 + o];
#pragma unroll
  for (int i = 0; i < 4; ++i) {
    const int n = n0 + ng * 4 + i;
    float4 r = make_float4(acc[i][0] + bo[0], acc[i][1] + bo[1],
                           acc[i][2] + bo[2], acc[i][3] + bo[3]);
    *(float4*)&out[(size_t)n * NO + og * 4] = r;
  }
}

// ---------------------------------------------------------------------------
extern "C" void kernel_launch(void* const* d_in, const int* in_sizes, int n_in,
                              void* d_out, int out_size, void* d_ws, size_t ws_size,
                              hipStream_t stream) {
  const float* x     = (const float*)d_in[0];
  const float* W     = (const float*)d_in[1];
  const float* b     = (const float*)d_in[2];
  const float* W_out = (const float*)d_in[3];
  const float* b_out = (const float*)d_in[4];
  const int*   erows = (const int*)d_in[5];
  const int*   ecols = (const int*)d_in[6];
  const float* evals = (const float*)d_in[7];
  float* out = (float*)d_out;

  // ws layout (bytes), total ~118e6 (<128e6 known-safe):
  //   slots: 5 x NNODES*NH bf16 = 64.0e6   (agg[k]=slot k, hb[k]=slot k+1;
  //          aliasing is safe ONLY because gathers are sequential dispatches)
  //   xb: NPAD*NF bf16 = 25.7e6 | Wt: 0.26e6 | ecsr: 25.6e6 | ints 2.4e6
  unsigned short* slots = (unsigned short*)d_ws;
  unsigned short* xb = slots + (size_t)(NHOPS + 1) * NNODES * NH;
  unsigned short* Wt = xb + (size_t)NPAD * NF;
  unsigned long long* ecsr = (unsigned long long*)(Wt + (size_t)NHOPS * NH * NF);
  int* counts = (int*)(ecsr + (size_t)NHOPS * NEDGES);
  int* offs   = counts + NHOPS * NNODES;
  int* cursor = offs + NHOPS * (NNODES + 1);

  hipMemsetAsync(counts, 0, (size_t)NHOPS * NNODES * sizeof(int), stream);

  phaseA_kernel<<<CONVX_BLOCKS + CONVW_BLOCKS + HIST_BLOCKS, 256, 0, stream>>>(
      x, xb, W, Wt, erows, counts);
  scan_kernel<<<NHOPS, 1024, 0, stream>>>(counts, offs, cursor);
  phaseC_kernel<<<PC_BLOCKS, 256, 0, stream>>>(
      xb, Wt, b, slots, erows, ecols, evals, cursor, ecsr);

  for (int k = 0; k < NHOPS; ++k) {
    gather_kernel<<<NNODES / 4, 256, 0, stream>>>(
        offs + (size_t)k * (NNODES + 1), (const int2*)(ecsr + (size_t)k * NEDGES),
        slots + (size_t)(k + 1) * NNODES * NH,   // hb[k]
        slots + (size_t)k * NNODES * NH);        // agg[k]
  }

  out_kernel<<<NNODES / 16, 64, 0, stream>>>(slots, W_out, b_out, out);
}

// Round 7
// 880.081 us; speedup vs baseline: 1.2859x; 1.2859x over previous
//
#include <hip/hip_runtime.h>
#include <hip/hip_bf16.h>
#include <math.h>

#define NNODES 50000
#define NPAD   50176              // 392*128, padded rows for MFMA tile overrun
#define NEDGES 800000
#define NHOPS  4
#define NF     256
#define NH     128
#define NO     64

#define CONVX_BLOCKS 12500        // NNODES*NF/4/256
#define CONVW_BLOCKS 512          // NHOPS*NH*NF/256
#define HIST_BLOCKS  12500        // (NEDGES/256)*NHOPS
#define LIN_PER_HOP  391          // ceil(NNODES/128)
#define LIN_BLOCKS   (LIN_PER_HOP * NHOPS)     // 1564

typedef __attribute__((ext_vector_type(8))) short bfrag_t;   // 8 x bf16
typedef __attribute__((ext_vector_type(4))) float facc_t;    // 4 x f32

static __device__ __forceinline__ unsigned short f2bf(float f) {
  unsigned int u = __float_as_uint(f);
  unsigned int r = (u + 0x7fffu + ((u >> 16) & 1u)) >> 16;
  return (unsigned short)r;
}
static __device__ __forceinline__ float bf2f_lo(unsigned int u) {
  return __uint_as_float(u << 16);
}
static __device__ __forceinline__ float bf2f_hi(unsigned int u) {
  return __uint_as_float(u & 0xffff0000u);
}

// ---------------------------------------------------------------------------
// Phase A (fused): convx | convw | hist. All independent.
// hist atomics are fire-and-forget (result unused -> no-return form).
// ---------------------------------------------------------------------------
__global__ __launch_bounds__(256) void phaseA_kernel(
    const float* __restrict__ x, unsigned short* __restrict__ xb,
    const float* __restrict__ W, unsigned short* __restrict__ Wt,
    const int* __restrict__ erows, int* __restrict__ counts) {
  const int bx = blockIdx.x;
  const int t  = threadIdx.x;
  if (bx < CONVX_BLOCKS) {
    const size_t i = ((size_t)bx * 256 + t) * 4;
    float4 v = *(const float4*)&x[i];
    ushort4 o;
    o.x = f2bf(v.x); o.y = f2bf(v.y); o.z = f2bf(v.z); o.w = f2bf(v.w);
    *(ushort4*)&xb[i] = o;
  } else if (bx < CONVX_BLOCKS + CONVW_BLOCKS) {
    const int i = (bx - CONVX_BLOCKS) * 256 + t;
    const int k = i / (NH * NF);
    const int rem = i - k * NH * NF;
    const int n = rem / NF;
    const int f = rem - n * NF;
    Wt[i] = f2bf(W[(size_t)k * NF * NH + (size_t)f * NH + n]);
  } else {
    const int id  = bx - (CONVX_BLOCKS + CONVW_BLOCKS);
    const int hop = id / 3125;
    const int e   = (id - hop * 3125) * 256 + t;
    const int r = erows[(size_t)hop * NEDGES + e];
    atomicAdd(&counts[hop * NNODES + r], 1);
  }
}

// ---------------------------------------------------------------------------
// CSR build step 2: exclusive scan per hop. 8 items/thread -> 7 chunk iters.
// ---------------------------------------------------------------------------
__global__ __launch_bounds__(1024) void scan_kernel(
    const int* __restrict__ counts, int* __restrict__ offs,
    int* __restrict__ cursor) {
  const int hop  = blockIdx.x;
  const int t    = threadIdx.x;
  const int lane = t & 63;
  const int wid  = t >> 6;
  __shared__ int wsum[16];
  __shared__ int carry_s;
  if (t == 0) carry_s = 0;
  __syncthreads();
  const int CH  = 8192;
  const int nch = (NNODES + CH - 1) / CH;     // 7
  for (int ch = 0; ch < nch; ++ch) {
    const int i0 = ch * CH + t * 8;
    int v[8];
    if (i0 + 7 < NNODES) {
      int4 a = *(const int4*)&counts[hop * NNODES + i0];
      int4 b = *(const int4*)&counts[hop * NNODES + i0 + 4];
      v[0]=a.x; v[1]=a.y; v[2]=a.z; v[3]=a.w;
      v[4]=b.x; v[5]=b.y; v[6]=b.z; v[7]=b.w;
    } else {
#pragma unroll
      for (int j = 0; j < 8; ++j)
        v[j] = (i0 + j < NNODES) ? counts[hop * NNODES + i0 + j] : 0;
    }
    int l[8];
    int run = 0;
#pragma unroll
    for (int j = 0; j < 8; ++j) { run += v[j]; l[j] = run; }   // inclusive
    int s = run;
#pragma unroll
    for (int d = 1; d < 64; d <<= 1) {
      int n = __shfl_up(s, d, 64);
      if (lane >= d) s += n;
    }
    if (lane == 63) wsum[wid] = s;
    __syncthreads();
    if (t < 16) {
      int ws = wsum[t];
#pragma unroll
      for (int d = 1; d < 16; d <<= 1) {
        int n = __shfl_up(ws, d, 16);
        if (t >= d) ws += n;
      }
      wsum[t] = ws;
    }
    __syncthreads();
    const int base = carry_s + (wid ? wsum[wid - 1] : 0) + (s - run);
    if (i0 + 7 < NNODES) {
      int4 o0 = make_int4(base, base + l[0], base + l[1], base + l[2]);
      int4 o1 = make_int4(base + l[3], base + l[4], base + l[5], base + l[6]);
      *(int4*)&offs[hop * (NNODES + 1) + i0]     = o0;
      *(int4*)&offs[hop * (NNODES + 1) + i0 + 4] = o1;
      *(int4*)&cursor[hop * NNODES + i0]     = o0;
      *(int4*)&cursor[hop * NNODES + i0 + 4] = o1;
    } else {
#pragma unroll
      for (int j = 0; j < 8; ++j) {
        if (i0 + j < NNODES) {
          const int excl = base + (l[j] - v[j]);
          offs[hop * (NNODES + 1) + i0 + j] = excl;
          cursor[hop * NNODES + i0 + j]     = excl;
        }
      }
    }
    __syncthreads();
    if (t == 0) carry_s += wsum[15];
    __syncthreads();
  }
  if (t == 0) offs[hop * (NNODES + 1) + NNODES] = carry_s;
}

// ---------------------------------------------------------------------------
// Linear via MFMA, all 4 hops in one dispatch (1564 blocks).
// Block = 256 thr = 4 waves (2x2), each wave 64x64 via 4x4 16x16x32 tiles.
// (R6 lesson: do NOT interleave with scatter — heterogeneous block mix
//  halves resident scatter waves and regresses 2x.)
// ---------------------------------------------------------------------------
__global__ __launch_bounds__(256) void linear_kernel(
    const unsigned short* __restrict__ xb, const unsigned short* __restrict__ Wt,
    const float* __restrict__ b, unsigned short* __restrict__ slots) {
  const int lb  = blockIdx.x;
  const int hop = lb / LIN_PER_HOP;
  const int mb  = lb - hop * LIN_PER_HOP;
  const unsigned short* Wk = Wt + (size_t)hop * NH * NF;
  const float* bk = b + hop * NH;
  unsigned short* hb = slots + (size_t)(hop + 1) * NNODES * NH;

  const int t    = threadIdx.x;
  const int lane = t & 63;
  const int wave = t >> 6;
  const int wm   = (wave >> 1) * 64;
  const int wn   = (wave & 1) * 64;
  const int m0   = mb * 128;
  const int l15  = lane & 15;
  const int quad = lane >> 4;

  facc_t acc[4][4];
#pragma unroll
  for (int i = 0; i < 4; ++i)
#pragma unroll
    for (int j = 0; j < 4; ++j) {
      facc_t z = {0.f, 0.f, 0.f, 0.f};
      acc[i][j] = z;
    }

#pragma unroll
  for (int k0 = 0; k0 < NF; k0 += 32) {
    bfrag_t a[4], bb[4];
#pragma unroll
    for (int mi = 0; mi < 4; ++mi) {
      const int m = m0 + wm + mi * 16 + l15;
      a[mi] = *(const bfrag_t*)&xb[(size_t)m * NF + k0 + quad * 8];
    }
#pragma unroll
    for (int ni = 0; ni < 4; ++ni) {
      const int n = wn + ni * 16 + l15;
      bb[ni] = *(const bfrag_t*)&Wk[(size_t)n * NF + k0 + quad * 8];
    }
#pragma unroll
    for (int mi = 0; mi < 4; ++mi)
#pragma unroll
      for (int ni = 0; ni < 4; ++ni)
        acc[mi][ni] = __builtin_amdgcn_mfma_f32_16x16x32_bf16(
            a[mi], bb[ni], acc[mi][ni], 0, 0, 0);
  }

#pragma unroll
  for (int ni = 0; ni < 4; ++ni) {
    const int n = wn + ni * 16 + l15;
    const float bias = bk[n];
#pragma unroll
    for (int mi = 0; mi < 4; ++mi) {
#pragma unroll
      for (int r = 0; r < 4; ++r) {
        const int m = m0 + wm + mi * 16 + quad * 4 + r;
        if (m < NNODES) hb[(size_t)m * NH + n] = f2bf(acc[mi][ni][r] + bias);
      }
    }
  }
}

// ---------------------------------------------------------------------------
// CSR scatter: 4 edges per thread (int4/float4 loads) -> 4 independent
// atomic->store chains in flight per thread (4x MLP vs R4's 1/thread).
// Nontemporal 8B stores (no L2 line churn). grid = (782, NHOPS).
// ---------------------------------------------------------------------------
__global__ __launch_bounds__(256) void scatter_kernel(
    const int* __restrict__ erows, const int* __restrict__ ecols,
    const float* __restrict__ evals, int* __restrict__ cursor,
    unsigned long long* __restrict__ ecsr) {
  const int hop  = blockIdx.y;
  const int base = (blockIdx.x * 256 + threadIdx.x) * 4;
  if (base >= NEDGES) return;
  const size_t g0 = (size_t)hop * NEDGES + base;
  int* cur = cursor + hop * NNODES;
  unsigned long long* dst = ecsr + (size_t)hop * NEDGES;

  if (base + 3 < NEDGES) {
    const int4   rr = *(const int4*)&erows[g0];
    const int4   cc = *(const int4*)&ecols[g0];
    const float4 vv = *(const float4*)&evals[g0];
    const int r[4] = {rr.x, rr.y, rr.z, rr.w};
    const int c[4] = {cc.x, cc.y, cc.z, cc.w};
    const float v[4] = {vv.x, vv.y, vv.z, vv.w};
    int pos[4];
#pragma unroll
    for (int j = 0; j < 4; ++j) pos[j] = atomicAdd(&cur[r[j]], 1);
#pragma unroll
    for (int j = 0; j < 4; ++j) {
      const unsigned long long pk =
          ((unsigned long long)__float_as_uint(v[j]) << 32) | (unsigned int)c[j];
      __builtin_nontemporal_store(pk, &dst[pos[j]]);
    }
  } else {
    for (int j = 0; j < 4 && base + j < NEDGES; ++j) {
      const int r = erows[g0 + j];
      const int pos = atomicAdd(&cur[r], 1);
      const unsigned long long pk =
          ((unsigned long long)__float_as_uint(evals[g0 + j]) << 32) |
          (unsigned int)ecols[g0 + j];
      __builtin_nontemporal_store(pk, &dst[pos]);
    }
  }
}

// ---------------------------------------------------------------------------
// Gather SpMM (ONE HOP per dispatch — sequential dispatches enforce the
// hb[k]/agg[k] slot-aliasing dependency; fusing hops raced in R5).
// 1 wave/row; wave = 4 edge-groups x 16 lanes x 16B; 16 edges in flight.
// ---------------------------------------------------------------------------
__global__ __launch_bounds__(256) void gather_kernel(
    const int* __restrict__ offs, const int2* __restrict__ ecsr,
    const unsigned short* __restrict__ hb, unsigned short* __restrict__ aggb) {
  const int t    = threadIdx.x;
  const int lane = t & 63;
  const int wid  = t >> 6;
  const int r = blockIdx.x * 4 + wid;
  const int g  = lane >> 4;    // edge subgroup 0..3
  const int sl = lane & 15;    // feature slice: feats sl*8 .. sl*8+7
  const int s = offs[r];
  const int e = offs[r + 1];

  float acc[8];
#pragma unroll
  for (int j = 0; j < 8; ++j) acc[j] = 0.f;

  for (int p = s; p < e; p += 16) {
    int2 ed[4];
#pragma unroll
    for (int q = 0; q < 4; ++q) {
      const int idx = p + q * 4 + g;
      ed[q] = (idx < e) ? ecsr[idx] : make_int2(0, 0);
    }
    uint4 hv[4];
#pragma unroll
    for (int q = 0; q < 4; ++q)
      hv[q] = *(const uint4*)&hb[(size_t)ed[q].x * NH + sl * 8];
#pragma unroll
    for (int q = 0; q < 4; ++q) {
      const float v = __int_as_float(ed[q].y);
      acc[0] += v * bf2f_lo(hv[q].x);
      acc[1] += v * bf2f_hi(hv[q].x);
      acc[2] += v * bf2f_lo(hv[q].y);
      acc[3] += v * bf2f_hi(hv[q].y);
      acc[4] += v * bf2f_lo(hv[q].z);
      acc[5] += v * bf2f_hi(hv[q].z);
      acc[6] += v * bf2f_lo(hv[q].w);
      acc[7] += v * bf2f_hi(hv[q].w);
    }
  }

#pragma unroll
  for (int j = 0; j < 8; ++j) {
    acc[j] += __shfl_xor(acc[j], 16, 64);
    acc[j] += __shfl_xor(acc[j], 32, 64);
  }

  if (g == 0) {
    uint4 o;
    o.x = (unsigned)f2bf(acc[0]) | ((unsigned)f2bf(acc[1]) << 16);
    o.y = (unsigned)f2bf(acc[2]) | ((unsigned)f2bf(acc[3]) << 16);
    o.z = (unsigned)f2bf(acc[4]) | ((unsigned)f2bf(acc[5]) << 16);
    o.w = (unsigned)f2bf(acc[6]) | ((unsigned)f2bf(acc[7]) << 16);
    *(uint4*)&aggb[(size_t)r * NH + sl * 8] = o;
  }
}

// ---------------------------------------------------------------------------
// Output: out[n][o] = b_out[o] + sum_f elu(concat[n][f]) * W_out[f][o]
// ---------------------------------------------------------------------------
__global__ __launch_bounds__(64) void out_kernel(
    const unsigned short* __restrict__ aggb, const float* __restrict__ Wout,
    const float* __restrict__ bout, float* __restrict__ out) {
  __shared__ float zs[16 * 516];
  const int t  = threadIdx.x;
  const int n0 = blockIdx.x * 16;

#pragma unroll
  for (int cch = 0; cch < 32; ++cch) {
    const int flat = cch * 256 + t * 4;
    const int n_l  = flat >> 9;
    const int f    = flat & 511;
    const int k    = f >> 7;
    const int j    = f & 127;
    const uint2 u = *(const uint2*)&aggb[((size_t)k * NNODES + n0 + n_l) * NH + j];
    float4 v = make_float4(bf2f_lo(u.x), bf2f_hi(u.x), bf2f_lo(u.y), bf2f_hi(u.y));
    v.x = v.x > 0.f ? v.x : (expf(v.x) - 1.f);
    v.y = v.y > 0.f ? v.y : (expf(v.y) - 1.f);
    v.z = v.z > 0.f ? v.z : (expf(v.z) - 1.f);
    v.w = v.w > 0.f ? v.w : (expf(v.w) - 1.f);
    *(float4*)&zs[n_l * 516 + f] = v;
  }
  __syncthreads();

  const int og = t & 15;
  const int ng = t >> 4;
  float acc[4][4];
#pragma unroll
  for (int i = 0; i < 4; ++i)
#pragma unroll
    for (int o = 0; o < 4; ++o) acc[i][o] = 0.f;

  for (int fq = 0; fq < 128; ++fq) {
    const int f = fq * 4;
    float4 z[4], w[4];
#pragma unroll
    for (int i = 0; i < 4; ++i)
      z[i] = *(float4*)&zs[(ng * 4 + i) * 516 + f];
#pragma unroll
    for (int u = 0; u < 4; ++u)
      w[u] = *(const float4*)&Wout[(size_t)(f + u) * NO + og * 4];
    float zv[4][4] = {{z[0].x, z[0].y, z[0].z, z[0].w},
                      {z[1].x, z[1].y, z[1].z, z[1].w},
                      {z[2].x, z[2].y, z[2].z, z[2].w},
                      {z[3].x, z[3].y, z[3].z, z[3].w}};
    float wv[4][4] = {{w[0].x, w[0].y, w[0].z, w[0].w},
                      {w[1].x, w[1].y, w[1].z, w[1].w},
                      {w[2].x, w[2].y, w[2].z, w[2].w},
                      {w[3].x, w[3].y, w[3].z, w[3].w}};
#pragma unroll
    for (int i = 0; i < 4; ++i)
#pragma unroll
      for (int u = 0; u < 4; ++u)
#pragma unroll
        for (int o = 0; o < 4; ++o) acc[i][o] += zv[i][u] * wv[u][o];
  }

  float bo[4];
#pragma unroll
  for (int o = 0; o < 4; ++o) bo[o] = bout[og * 4 + o];
#pragma unroll
  for (int i = 0; i < 4; ++i) {
    const int n = n0 + ng * 4 + i;
    float4 r = make_float4(acc[i][0] + bo[0], acc[i][1] + bo[1],
                           acc[i][2] + bo[2], acc[i][3] + bo[3]);
    *(float4*)&out[(size_t)n * NO + og * 4] = r;
  }
}

// ---------------------------------------------------------------------------
extern "C" void kernel_launch(void* const* d_in, const int* in_sizes, int n_in,
                              void* d_out, int out_size, void* d_ws, size_t ws_size,
                              hipStream_t stream) {
  const float* x     = (const float*)d_in[0];
  const float* W     = (const float*)d_in[1];
  const float* b     = (const float*)d_in[2];
  const float* W_out = (const float*)d_in[3];
  const float* b_out = (const float*)d_in[4];
  const int*   erows = (const int*)d_in[5];
  const int*   ecols = (const int*)d_in[6];
  const float* evals = (const float*)d_in[7];
  float* out = (float*)d_out;

  // ws layout (bytes), total ~118e6 (<128e6 known-safe):
  //   slots: 5 x NNODES*NH bf16 = 64.0e6   (agg[k]=slot k, hb[k]=slot k+1;
  //          aliasing is safe ONLY because gathers are sequential dispatches)
  //   xb: NPAD*NF bf16 = 25.7e6 | Wt: 0.26e6 | ecsr: 25.6e6 | ints 2.4e6
  unsigned short* slots = (unsigned short*)d_ws;
  unsigned short* xb = slots + (size_t)(NHOPS + 1) * NNODES * NH;
  unsigned short* Wt = xb + (size_t)NPAD * NF;
  unsigned long long* ecsr = (unsigned long long*)(Wt + (size_t)NHOPS * NH * NF);
  int* counts = (int*)(ecsr + (size_t)NHOPS * NEDGES);
  int* offs   = counts + NHOPS * NNODES;
  int* cursor = offs + NHOPS * (NNODES + 1);

  hipMemsetAsync(counts, 0, (size_t)NHOPS * NNODES * sizeof(int), stream);

  phaseA_kernel<<<CONVX_BLOCKS + CONVW_BLOCKS + HIST_BLOCKS, 256, 0, stream>>>(
      x, xb, W, Wt, erows, counts);
  scan_kernel<<<NHOPS, 1024, 0, stream>>>(counts, offs, cursor);
  linear_kernel<<<LIN_BLOCKS, 256, 0, stream>>>(xb, Wt, b, slots);
  scatter_kernel<<<dim3(782, NHOPS), 256, 0, stream>>>(
      erows, ecols, evals, cursor, ecsr);

  for (int k = 0; k < NHOPS; ++k) {
    gather_kernel<<<NNODES / 4, 256, 0, stream>>>(
        offs + (size_t)k * (NNODES + 1), (const int2*)(ecsr + (size_t)k * NEDGES),
        slots + (size_t)(k + 1) * NNODES * NH,   // hb[k]
        slots + (size_t)k * NNODES * NH);        // agg[k]
  }

  out_kernel<<<NNODES / 16, 64, 0, stream>>>(slots, W_out, b_out, out);
}